// Round 9
// baseline (535.812 us; speedup 1.0000x reference)
//
#include <hip/hip_runtime.h>
#include <hip/hip_bf16.h>

typedef __attribute__((ext_vector_type(8))) short  bf16x8;  // 8 bf16 = 4 VGPRs
typedef __attribute__((ext_vector_type(4))) float  f32x4;   // mfma 16x16 C/D

__device__ __forceinline__ ushort f2bf(float f) {
    unsigned u = __builtin_bit_cast(unsigned, f);
    u += 0x7fffu + ((u >> 16) & 1u);   // round-to-nearest-even
    return (ushort)(u >> 16);
}

// packed f32x2 -> bf16x2 (RNE), single VALU op
__device__ __forceinline__ unsigned cvt_pk_bf16(float a, float b) {
    unsigned r;
    asm("v_cvt_pk_bf16_f32 %0, %1, %2" : "=v"(r) : "v"(a), "v"(b));
    return r;
}

// raw v_exp_f32 (2^x). exp2f without fast-math lowers to OCML's guarded
// sequence (~5 VALU); our S values are bounded so the fixup is pure waste.
// (Proven r8: VALUBusy 67->37%.)
__device__ __forceinline__ float fexp2(float x) {
    float r;
    asm("v_exp_f32 %0, %1" : "=v"(r) : "v"(x));
    return r;
}

// async global->LDS, 16B/lane; LDS dest = wave-uniform base + lane*16 (m97/m104)
__device__ __forceinline__ void gload_lds16(const ushort* g, ushort* l) {
    __builtin_amdgcn_global_load_lds(
        (const __attribute__((address_space(1))) void*)(g),
        (__attribute__((address_space(3))) void*)(l), 16, 0, 0);
}

// raw s_barrier (no implicit waitcnt) with compiler/scheduler fences: counted
// vmcnt prefetch rides across it.
__device__ __forceinline__ void blockbar() {
    asm volatile("" ::: "memory");
    __builtin_amdgcn_sched_barrier(0);
    __builtin_amdgcn_s_barrier();
    __builtin_amdgcn_sched_barrier(0);
    asm volatile("" ::: "memory");
}
#define SFENCE() __builtin_amdgcn_sched_barrier(0)

// ---------------------------------------------------------------- fused prep
// blocks [0,16384): x f32 -> bf16. [16384,16576): Wqkv^T tiles. [16576,16640): Wproj^T.
__global__ __launch_bounds__(256) void prep_kernel(
        const float* __restrict__ x, ushort* __restrict__ xb,
        const float* __restrict__ Wqkv, ushort* __restrict__ wq,
        const float* __restrict__ Wproj, ushort* __restrict__ wp) {
    __shared__ ushort t[64 * 65];
    const int bx = blockIdx.x, tid = threadIdx.x;
    if (bx < 16384) {
        int i = bx * 256 + tid;
        float4 f = reinterpret_cast<const float4*>(x)[i];
        ushort4 o;
        o.x = f2bf(f.x); o.y = f2bf(f.y); o.z = f2bf(f.z); o.w = f2bf(f.w);
        reinterpret_cast<ushort4*>(xb)[i] = o;
        return;
    }
    const float* in; ushort* out; int Cc, qcols, cB, rB; float qs;
    if (bx < 16576) {
        int b2 = bx - 16384;                       // 192 = 24 x 8
        in = Wqkv; out = wq; Cc = 1536; qcols = 512;
        qs = 0.18033688011112043f;                 // 0.125 * log2(e) folded into Q
        cB = (b2 % 24) * 64; rB = (b2 / 24) * 64;
    } else {
        int b2 = bx - 16576;                       // 64 = 8 x 8
        in = Wproj; out = wp; Cc = 512; qcols = 0; qs = 1.0f;
        cB = (b2 % 8) * 64; rB = (b2 / 8) * 64;
    }
#pragma unroll
    for (int p = 0; p < 16; ++p) {
        int lin = p * 256 + tid;
        int r = lin >> 6, c = lin & 63;
        float v = in[(size_t)(rB + r) * Cc + cB + c];
        if (cB + c < qcols) v *= qs;
        t[c * 65 + r] = f2bf(v);
    }
    __syncthreads();
#pragma unroll
    for (int p = 0; p < 16; ++p) {
        int lin = p * 256 + tid;
        int c = lin >> 6, r = lin & 63;
        out[(size_t)(cB + c) * 512 + rB + r] = t[c * 65 + r];
    }
}

// ---------------------------------------------------------------- GEMM (all operands bf16 [rows][K])
// 256x256 tile, BK=64, 8 waves (2Mx4N), wave = 128x64 via 8x4 mfma 16x16x32.
// PROVEN rounds 2-5/7 (<73 us): 2-slot 128 KB LDS, counted cross-barrier
// prefetch; vmcnt never drains to 0 in the main loop.
// SPLIT_VT (GEMM1): blocks id<512 compute QK = xb.wqk^T (XCD-affine m digit).
// Blocks id>=512 compute V^T = wv.xb^T by operand swap (output natively [d][tok]).
template<bool F32OUT, bool SPLIT_VT>
__global__ __launch_bounds__(512, 2) void gemm_bt_kernel(
        const ushort* __restrict__ A, const ushort* __restrict__ Bt,
        void* __restrict__ Cout, const float* __restrict__ bias,
        const ushort* __restrict__ Wv, ushort* __restrict__ vT,
        int Ncols, int K) {
    __shared__ ushort smem[65536];   // 2 slots x (A 256x64 + B 256x64) bf16 = 128 KB
    const int tid = threadIdx.x;
    const int id  = blockIdx.x;
    const bool vt = SPLIT_VT && (id >= 512);
    const ushort* Amat; const ushort* Bmat; int mBase, nBase;
    if (!vt) {
        Amat = A; Bmat = Bt;
        mBase = ((id & 7) * 16 + ((id >> 3) & 15)) << 8;   // XCD-affine m digit
        nBase = (id >> 7) << 8;
    } else {
        int vid = id - 512;                                 // 256 = 2 d-tiles x 128 tok-tiles
        Amat = Wv; Bmat = A;
        mBase = (vid >> 7) << 8;                            // d-tile
        nBase = ((vid & 7) * 16 + ((vid >> 3) & 15)) << 8;  // token tile, XCD-affine
    }
    const int w = tid >> 6, lane = tid & 63, ml = lane & 15, quad = lane >> 4;
    const int wr = (w >> 2) * 128, wc = (w & 3) * 64;

    // staging: wave w covers rows [w*32, w*32+32); 4 instrs x 8 rows per matrix.
    // LDS[row][c] = G[row][c ^ (row&7)] via pre-swizzled per-lane global source.
    const int srow = lane >> 3;                 // 0..7
    const int sch  = (lane & 7) ^ srow;         // chunk ^ s(row)
    const ushort* Ap = Amat + (size_t)(mBase + w * 32 + srow) * K + sch * 8;
    const ushort* Bp = Bmat + (size_t)(nBase + w * 32 + srow) * K + sch * 8;

    f32x4 z4 = {0.f, 0.f, 0.f, 0.f};
    f32x4 acc[8][4];
#pragma unroll
    for (int i = 0; i < 8; ++i)
#pragma unroll
        for (int j = 0; j < 4; ++j) acc[i][j] = z4;

    auto stage = [&](int t, int slot) {          // 8 loads/wave -> vmcnt +8
        ushort* la_ = smem + slot * 32768;
        ushort* lb_ = la_ + 16384;
        const ushort* a = Ap + t * 64;
        const ushort* b = Bp + t * 64;
#pragma unroll
        for (int i = 0; i < 4; ++i) {
            gload_lds16(a + (size_t)(8 * i) * K, la_ + (w * 32 + 8 * i) * 64);
            gload_lds16(b + (size_t)(8 * i) * K, lb_ + (w * 32 + 8 * i) * 64);
        }
    };

    const int rdo0 = ((0 + quad) ^ (ml & 7)) << 3;   // ks=0 read chunk (row&7 == ml&7)
    const int rdo1 = ((4 + quad) ^ (ml & 7)) << 3;   // ks=1

    auto compute = [&](int slot) {
        ushort* la_ = smem + slot * 32768;
        ushort* lb_ = la_ + 16384;
        bf16x8 bv[4][2];
#pragma unroll
        for (int fn = 0; fn < 4; ++fn) {
            ushort* r = lb_ + (wc + fn * 16 + ml) * 64;
            bv[fn][0] = *reinterpret_cast<bf16x8*>(r + rdo0);
            bv[fn][1] = *reinterpret_cast<bf16x8*>(r + rdo1);
        }
#pragma unroll
        for (int mh = 0; mh < 2; ++mh) {         // split A-half: caps live regs
            bf16x8 af[4][2];
#pragma unroll
            for (int fm = 0; fm < 4; ++fm) {
                ushort* r = la_ + (wr + mh * 64 + fm * 16 + ml) * 64;
                af[fm][0] = *reinterpret_cast<bf16x8*>(r + rdo0);
                af[fm][1] = *reinterpret_cast<bf16x8*>(r + rdo1);
            }
            __builtin_amdgcn_s_setprio(1);
#pragma unroll
            for (int ks = 0; ks < 2; ++ks)
#pragma unroll
                for (int fm = 0; fm < 4; ++fm)
#pragma unroll
                    for (int fn = 0; fn < 4; ++fn)
                        acc[mh * 4 + fm][fn] = __builtin_amdgcn_mfma_f32_16x16x32_bf16(
                            af[fm][ks], bv[fn][ks], acc[mh * 4 + fm][fn], 0, 0, 0);
            __builtin_amdgcn_s_setprio(0);
        }
    };

    const int nkt = K >> 6;                       // = 8 for K=512
    stage(0, 0); SFENCE();                        // keep tile0 loads oldest
    stage(1, 1); SFENCE();
    for (int t = 0; t < nkt - 1; ++t) {
        asm volatile("s_waitcnt vmcnt(8)" ::: "memory");   // tile t ready; t+1 in flight
        blockbar();
        compute(t & 1);
        blockbar();                               // slot t&1 free for overwrite
        if (t + 2 < nkt) { stage(t + 2, t & 1); SFENCE(); }
    }
    asm volatile("s_waitcnt vmcnt(0)" ::: "memory");       // epilogue drain
    blockbar();
    compute((nkt - 1) & 1);
    // no barrier needed: epilogue scratch lives in slot0 bytes, final compute
    // read slot1, and each wave's epilogue region is private.

    // ---- epilogue via per-wave LDS transpose -> coalesced wide stores ----
    if (F32OUT) {
        float* ep = reinterpret_cast<float*>(smem) + w * 1088;   // 16 rows x 68 f32
        float bj[4];
#pragma unroll
        for (int j = 0; j < 4; ++j) bj[j] = bias[nBase + wc + j * 16 + ml];
        float* cbase = reinterpret_cast<float*>(Cout);
#pragma unroll
        for (int i = 0; i < 8; ++i) {
#pragma unroll
            for (int j = 0; j < 4; ++j)
#pragma unroll
                for (int r = 0; r < 4; ++r)
                    ep[(quad * 4 + r) * 68 + j * 16 + ml] = acc[i][j][r] + bj[j];
#pragma unroll
            for (int t = 0; t < 4; ++t) {
                int ch = quad + 4 * t;
                float4 v = *reinterpret_cast<const float4*>(ep + ml * 68 + ch * 4);
                *reinterpret_cast<float4*>(cbase
                    + (size_t)(mBase + wr + i * 16 + ml) * Ncols + nBase + wc + ch * 4) = v;
            }
        }
    } else {
        ushort* ep = smem + w * 1152;   // 16 rows x 72 bf16
#pragma unroll
        for (int i = 0; i < 8; ++i) {
#pragma unroll
            for (int j = 0; j < 4; ++j)
#pragma unroll
                for (int r = 0; r < 4; ++r)
                    ep[(quad * 4 + r) * 72 + j * 16 + ml] = f2bf(acc[i][j][r]);
#pragma unroll
            for (int t = 0; t < 2; ++t) {
                int ch = quad + 4 * t;
                bf16x8 v = *reinterpret_cast<const bf16x8*>(ep + ml * 72 + ch * 8);
                int row = mBase + wr + i * 16 + ml;
                if (!vt) {
                    *reinterpret_cast<bf16x8*>(reinterpret_cast<ushort*>(Cout)
                        + (size_t)row * Ncols + nBase + wc + ch * 8) = v;
                } else {
                    // row = d-global (h*64+d), cols = tokens; group = nBase>>9
                    *reinterpret_cast<bf16x8*>(vT
                        + ((size_t)((nBase >> 9) * 512 + row)) * 512
                        + (nBase & 511) + wc + ch * 8) = v;
                }
            }
        }
    }
}

// ---------------------------------------------------------------- flash attention
// qk: [32768][1024] bf16 (Q 0..511 pre-scaled by 0.125*log2e, K 512..1023).
// vT: [(b*8+g)*512 + h*64+d][512 tokens] bf16.  out: [32768][512] bf16.
// Round-9 restructure (r8 showed all pipes low -> per-kt barrier-drain bound):
// 8 waves / 512 threads / 256 q-rows per block, grid 1024. Decode qc=(id>>3)&1,
// bgh=(id&7)|((id>>4)<<3): siblings {base, base+8} same XCD, adjacent (r5-proven).
// K/V 2-slot double-buffer with the GEMM-PROVEN counted cross-barrier schedule:
// stage(t+2) after the post-compute barrier; entry s_waitcnt vmcnt(2) -- own
// tile-t loads (oldest) done, tile-t+1's 2 loads ride across both raw barriers
// plus a full iteration of MFMA+exp. vmcnt never 0 in-loop. Occupancy cost of
// the dbuf is ZERO: VGPR (~70) already caps at 3 blocks/CU, and 50 KB LDS also
// gives 3 -- same 24 waves/CU as r8's single-buffer, minus the per-kt drain.
__global__ __launch_bounds__(512, 6) void attn_kernel(
        const ushort* __restrict__ qk, const ushort* __restrict__ vT,
        ushort* __restrict__ out) {
    __shared__ ushort k_lds[2][64 * 64];    // K tile [tok][d], XOR-swizzled chunks
    __shared__ ushort v_lds[2][64 * 64];    // V^T tile [d][tok], XOR-swizzled chunks
    __shared__ ushort p_lds[8 * 32 * 36];   // per-wave P [q=32][tok-half=32+pad4]
    const int tid = threadIdx.x;
    const int w = tid >> 6, lane = tid & 63, ml = lane & 15, quad = lane >> 4;
    const int id = blockIdx.x;
    const int qc = (id >> 3) & 1;
    const int bgh = (id & 7) | ((id >> 4) << 3);
    const int b = bgh >> 6, g = (bgh >> 3) & 7, h = bgh & 7;
    const int tb = b * 4096 + g * 512;
    const ushort* base  = qk + (size_t)tb * 1024 + h * 64;
    const ushort* vbase = vT + ((size_t)((b * 8 + g) * 512 + h * 64)) * 512;
    const int qOff = qc * 256 + w * 32;

    // Q fragments (B-operand for S^T: B[k=d=quad*8+j][n=q=ml]) -- 4 global
    // loads, issued FIRST (oldest in the vmcnt stream; covered by vmcnt(2)).
    bf16x8 qf[2][2];
#pragma unroll
    for (int qb = 0; qb < 2; ++qb)
#pragma unroll
        for (int ks = 0; ks < 2; ++ks)
            qf[qb][ks] = *reinterpret_cast<const bf16x8*>(
                base + (size_t)(qOff + qb * 16 + ml) * 1024 + ks * 32 + quad * 8);
    SFENCE();   // pin qf loads before staging in issue order

    // staging: wave w covers rows [w*8, w*8+8) of each 64-row tile: ONE
    // gload_lds16 per matrix per tile (8 waves x 8 rows = 64).
    const int srow = lane >> 3;                 // 0..7
    const int sch  = (lane & 7) ^ srow;
    const ushort* kp = base + (size_t)(w * 8 + srow) * 1024 + 512 + sch * 8;
    const ushort* vp = vbase + (size_t)(w * 8 + srow) * 512 + sch * 8;

    auto stage = [&](int kt, int slot) {         // 2 loads/wave -> vmcnt +2
        gload_lds16(kp + (size_t)(kt * 64) * 1024, k_lds[slot] + (w * 8) * 64);
        gload_lds16(vp + kt * 64,                  v_lds[slot] + (w * 8) * 64);
    };

    const bf16x8 onesf = {0x3f80, 0x3f80, 0x3f80, 0x3f80,
                          0x3f80, 0x3f80, 0x3f80, 0x3f80};   // bf16 1.0

    f32x4 z4 = {0.f, 0.f, 0.f, 0.f};
    f32x4 oacc[2][4];
    f32x4 sacc[2];           // row-sum accumulator (denominator), on MFMA pipe
#pragma unroll
    for (int qb = 0; qb < 2; ++qb) {
#pragma unroll
        for (int db = 0; db < 4; ++db) oacc[qb][db] = z4;
        sacc[qb] = z4;
    }

    ushort* pw = p_lds + w * 32 * 36;

    auto compute = [&](int buf) {
        // --- S^T = K.Q^T: A=K-frag A[m=tok][k=d], two ks(d)-slices
        f32x4 s[2][4];
#pragma unroll
        for (int qb = 0; qb < 2; ++qb)
#pragma unroll
            for (int kb = 0; kb < 4; ++kb) s[qb][kb] = z4;
#pragma unroll
        for (int ks = 0; ks < 2; ++ks) {
            bf16x8 kfs[4];
#pragma unroll
            for (int kb = 0; kb < 4; ++kb)
                kfs[kb] = *reinterpret_cast<bf16x8*>(
                    k_lds[buf] + (kb * 16 + ml) * 64 + (((ks * 4 + quad) ^ (ml & 7)) << 3));
            __builtin_amdgcn_s_setprio(1);
#pragma unroll
            for (int qb = 0; qb < 2; ++qb)
#pragma unroll
                for (int kb = 0; kb < 4; ++kb)
                    s[qb][kb] = __builtin_amdgcn_mfma_f32_16x16x32_bf16(kfs[kb], qf[qb][ks], s[qb][kb], 0, 0, 0);
            __builtin_amdgcn_s_setprio(0);
        }

        // --- per tok-half (ks): exp2 + pack + P-write, then O += P.V / den += P.1
        // (P half written & consumed before ks=1 overwrites: same-wave in-order DS)
#pragma unroll
        for (int ks = 0; ks < 2; ++ks) {
#pragma unroll
            for (int qb = 0; qb < 2; ++qb)
#pragma unroll
                for (int kbh = 0; kbh < 2; ++kbh) {
                    int kb = ks * 2 + kbh;
                    float p0 = fexp2(s[qb][kb][0]), p1 = fexp2(s[qb][kb][1]);
                    float p2 = fexp2(s[qb][kb][2]), p3 = fexp2(s[qb][kb][3]);
                    uint2 pk2;
                    pk2.x = cvt_pk_bf16(p0, p1);
                    pk2.y = cvt_pk_bf16(p2, p3);
                    *reinterpret_cast<uint2*>(
                        pw + (qb * 16 + ml) * 36 + kbh * 16 + quad * 4) = pk2;
                }
            bf16x8 pfs[2], vfs[4];
#pragma unroll
            for (int qb = 0; qb < 2; ++qb)
                pfs[qb] = *reinterpret_cast<bf16x8*>(
                    pw + (qb * 16 + ml) * 36 + quad * 8);
#pragma unroll
            for (int db = 0; db < 4; ++db)
                vfs[db] = *reinterpret_cast<bf16x8*>(
                    v_lds[buf] + (db * 16 + ml) * 64 + (((ks * 4 + quad) ^ (ml & 7)) << 3));
            __builtin_amdgcn_s_setprio(1);
#pragma unroll
            for (int qb = 0; qb < 2; ++qb)
                sacc[qb] = __builtin_amdgcn_mfma_f32_16x16x32_bf16(pfs[qb], onesf, sacc[qb], 0, 0, 0);
#pragma unroll
            for (int qb = 0; qb < 2; ++qb)
#pragma unroll
                for (int db = 0; db < 4; ++db)
                    oacc[qb][db] = __builtin_amdgcn_mfma_f32_16x16x32_bf16(pfs[qb], vfs[db], oacc[qb][db], 0, 0, 0);
            __builtin_amdgcn_s_setprio(0);
        }
    };

    stage(0, 0); SFENCE();
    stage(1, 1); SFENCE();
    for (int kt = 0; kt < 7; ++kt) {
        asm volatile("s_waitcnt vmcnt(2)" ::: "memory");   // tile kt done; kt+1 in flight
        blockbar();
        compute(kt & 1);
        blockbar();                                        // slot kt&1 free for overwrite
        if (kt + 2 < 8) { stage(kt + 2, kt & 1); SFENCE(); }
    }
    asm volatile("s_waitcnt vmcnt(0)" ::: "memory");       // last tile drain
    blockbar();
    compute(1);                                            // tile 7 in slot 1

    // --- epilogue: lanes hold their rows' sums in sacc -- reciprocal, store.
    float invq[2][4];
#pragma unroll
    for (int qb = 0; qb < 2; ++qb)
#pragma unroll
        for (int r = 0; r < 4; ++r)
            invq[qb][r] = 1.0f / sacc[qb][r];
#pragma unroll
    for (int qb = 0; qb < 2; ++qb)
#pragma unroll
        for (int db = 0; db < 4; ++db)
#pragma unroll
            for (int r = 0; r < 4; ++r) {
                float v = oacc[qb][db][r] * invq[qb][r];
                out[(size_t)(tb + qOff + qb * 16 + quad * 4 + r) * 512
                    + h * 64 + db * 16 + ml] = f2bf(v);
            }
}

// ---------------------------------------------------------------- launch
extern "C" void kernel_launch(void* const* d_in, const int* in_sizes, int n_in,
                              void* d_out, int out_size, void* d_ws, size_t ws_size,
                              hipStream_t stream) {
    const float* x     = (const float*)d_in[0];   // [8,4096,512]
    const float* Wqkv  = (const float*)d_in[1];   // [512,1536]
    const float* Wproj = (const float*)d_in[2];   // [512,512]
    const float* bproj = (const float*)d_in[3];   // [512]
    // d_in[4] recursive_index == 0 (static) -> num_groups = 8

    char* ws = (char*)d_ws;
    ushort* xb   = (ushort*)(ws);              // 32768*512  bf16 = 33,554,432 B
    ushort* wq   = (ushort*)(ws + 33554432);   // 1536*512   bf16 =  1,572,864 B
    ushort* wp   = (ushort*)(ws + 35127296);   //  512*512   bf16 =    524,288 B
    ushort* qkb  = (ushort*)(ws + 35651584);   // 32768*1024 bf16 = 67,108,864 B (Q,K)
    ushort* vTb  = (ushort*)(ws + 102760448);  // 32768*512  bf16 = 33,554,432 B
    ushort* attn = xb;                         // alias: x_bf16 dead after GEMM1
    ushort* wv   = wq + 1024 * 512;            // V-rows of Wqkv^T: [512 d][512 c]
    float*  outp = (float*)d_out;

    prep_kernel<<<16640, 256, 0, stream>>>(x, xb, Wqkv, wq, Wproj, wp);
    gemm_bt_kernel<false, true><<<768, 512, 0, stream>>>(
        xb, wq, qkb, nullptr, wv, vTb, 1024, 512);
    attn_kernel<<<1024, 512, 0, stream>>>(qkb, vTb, attn);
    gemm_bt_kernel<true, false><<<256, 512, 0, stream>>>(
        attn, wp, outp, bproj, nullptr, nullptr, 512, 512);
}

// Round 10
// 268.605 us; speedup vs baseline: 1.9948x; 1.9948x over previous
//
#include <hip/hip_runtime.h>
#include <hip/hip_bf16.h>

typedef __attribute__((ext_vector_type(8))) short  bf16x8;  // 8 bf16 = 4 VGPRs
typedef __attribute__((ext_vector_type(4))) float  f32x4;   // mfma 16x16 C/D

__device__ __forceinline__ ushort f2bf(float f) {
    unsigned u = __builtin_bit_cast(unsigned, f);
    u += 0x7fffu + ((u >> 16) & 1u);   // round-to-nearest-even
    return (ushort)(u >> 16);
}

// packed f32x2 -> bf16x2 (RNE), single VALU op
__device__ __forceinline__ unsigned cvt_pk_bf16(float a, float b) {
    unsigned r;
    asm("v_cvt_pk_bf16_f32 %0, %1, %2" : "=v"(r) : "v"(a), "v"(b));
    return r;
}

// raw v_exp_f32 (2^x). exp2f without fast-math lowers to OCML's guarded
// sequence (~5 VALU); our S values are bounded so the fixup is pure waste.
// (Proven r8: VALUBusy 67->37%.)
__device__ __forceinline__ float fexp2(float x) {
    float r;
    asm("v_exp_f32 %0, %1" : "=v"(r) : "v"(x));
    return r;
}

// async global->LDS, 16B/lane; LDS dest = wave-uniform base + lane*16 (m97/m104)
__device__ __forceinline__ void gload_lds16(const ushort* g, ushort* l) {
    __builtin_amdgcn_global_load_lds(
        (const __attribute__((address_space(1))) void*)(g),
        (__attribute__((address_space(3))) void*)(l), 16, 0, 0);
}

// raw s_barrier (no implicit waitcnt) with compiler/scheduler fences: counted
// vmcnt prefetch rides across it.
__device__ __forceinline__ void blockbar() {
    asm volatile("" ::: "memory");
    __builtin_amdgcn_sched_barrier(0);
    __builtin_amdgcn_s_barrier();
    __builtin_amdgcn_sched_barrier(0);
    asm volatile("" ::: "memory");
}
#define SFENCE() __builtin_amdgcn_sched_barrier(0)

// ---------------------------------------------------------------- fused prep
// blocks [0,16384): x f32 -> bf16. [16384,16576): Wqkv^T tiles. [16576,16640): Wproj^T.
__global__ __launch_bounds__(256) void prep_kernel(
        const float* __restrict__ x, ushort* __restrict__ xb,
        const float* __restrict__ Wqkv, ushort* __restrict__ wq,
        const float* __restrict__ Wproj, ushort* __restrict__ wp) {
    __shared__ ushort t[64 * 65];
    const int bx = blockIdx.x, tid = threadIdx.x;
    if (bx < 16384) {
        int i = bx * 256 + tid;
        float4 f = reinterpret_cast<const float4*>(x)[i];
        ushort4 o;
        o.x = f2bf(f.x); o.y = f2bf(f.y); o.z = f2bf(f.z); o.w = f2bf(f.w);
        reinterpret_cast<ushort4*>(xb)[i] = o;
        return;
    }
    const float* in; ushort* out; int Cc, qcols, cB, rB; float qs;
    if (bx < 16576) {
        int b2 = bx - 16384;                       // 192 = 24 x 8
        in = Wqkv; out = wq; Cc = 1536; qcols = 512;
        qs = 0.18033688011112043f;                 // 0.125 * log2(e) folded into Q
        cB = (b2 % 24) * 64; rB = (b2 / 24) * 64;
    } else {
        int b2 = bx - 16576;                       // 64 = 8 x 8
        in = Wproj; out = wp; Cc = 512; qcols = 0; qs = 1.0f;
        cB = (b2 % 8) * 64; rB = (b2 / 8) * 64;
    }
#pragma unroll
    for (int p = 0; p < 16; ++p) {
        int lin = p * 256 + tid;
        int r = lin >> 6, c = lin & 63;
        float v = in[(size_t)(rB + r) * Cc + cB + c];
        if (cB + c < qcols) v *= qs;
        t[c * 65 + r] = f2bf(v);
    }
    __syncthreads();
#pragma unroll
    for (int p = 0; p < 16; ++p) {
        int lin = p * 256 + tid;
        int c = lin >> 6, r = lin & 63;
        out[(size_t)(cB + c) * 512 + rB + r] = t[c * 65 + r];
    }
}

// ---------------------------------------------------------------- GEMM (all operands bf16 [rows][K])
// 256x256 tile, BK=64, 8 waves (2Mx4N), wave = 128x64 via 8x4 mfma 16x16x32.
// PROVEN rounds 2-5/7 (<73 us): 2-slot 128 KB LDS, counted cross-barrier
// prefetch; vmcnt never drains to 0 in the main loop.
// SPLIT_VT (GEMM1): blocks id<512 compute QK = xb.wqk^T (XCD-affine m digit).
// Blocks id>=512 compute V^T = wv.xb^T by operand swap (output natively [d][tok]).
template<bool F32OUT, bool SPLIT_VT>
__global__ __launch_bounds__(512, 2) void gemm_bt_kernel(
        const ushort* __restrict__ A, const ushort* __restrict__ Bt,
        void* __restrict__ Cout, const float* __restrict__ bias,
        const ushort* __restrict__ Wv, ushort* __restrict__ vT,
        int Ncols, int K) {
    __shared__ ushort smem[65536];   // 2 slots x (A 256x64 + B 256x64) bf16 = 128 KB
    const int tid = threadIdx.x;
    const int id  = blockIdx.x;
    const bool vt = SPLIT_VT && (id >= 512);
    const ushort* Amat; const ushort* Bmat; int mBase, nBase;
    if (!vt) {
        Amat = A; Bmat = Bt;
        mBase = ((id & 7) * 16 + ((id >> 3) & 15)) << 8;   // XCD-affine m digit
        nBase = (id >> 7) << 8;
    } else {
        int vid = id - 512;                                 // 256 = 2 d-tiles x 128 tok-tiles
        Amat = Wv; Bmat = A;
        mBase = (vid >> 7) << 8;                            // d-tile
        nBase = ((vid & 7) * 16 + ((vid >> 3) & 15)) << 8;  // token tile, XCD-affine
    }
    const int w = tid >> 6, lane = tid & 63, ml = lane & 15, quad = lane >> 4;
    const int wr = (w >> 2) * 128, wc = (w & 3) * 64;

    // staging: wave w covers rows [w*32, w*32+32); 4 instrs x 8 rows per matrix.
    // LDS[row][c] = G[row][c ^ (row&7)] via pre-swizzled per-lane global source.
    const int srow = lane >> 3;                 // 0..7
    const int sch  = (lane & 7) ^ srow;         // chunk ^ s(row)
    const ushort* Ap = Amat + (size_t)(mBase + w * 32 + srow) * K + sch * 8;
    const ushort* Bp = Bmat + (size_t)(nBase + w * 32 + srow) * K + sch * 8;

    f32x4 z4 = {0.f, 0.f, 0.f, 0.f};
    f32x4 acc[8][4];
#pragma unroll
    for (int i = 0; i < 8; ++i)
#pragma unroll
        for (int j = 0; j < 4; ++j) acc[i][j] = z4;

    auto stage = [&](int t, int slot) {          // 8 loads/wave -> vmcnt +8
        ushort* la_ = smem + slot * 32768;
        ushort* lb_ = la_ + 16384;
        const ushort* a = Ap + t * 64;
        const ushort* b = Bp + t * 64;
#pragma unroll
        for (int i = 0; i < 4; ++i) {
            gload_lds16(a + (size_t)(8 * i) * K, la_ + (w * 32 + 8 * i) * 64);
            gload_lds16(b + (size_t)(8 * i) * K, lb_ + (w * 32 + 8 * i) * 64);
        }
    };

    const int rdo0 = ((0 + quad) ^ (ml & 7)) << 3;   // ks=0 read chunk (row&7 == ml&7)
    const int rdo1 = ((4 + quad) ^ (ml & 7)) << 3;   // ks=1

    auto compute = [&](int slot) {
        ushort* la_ = smem + slot * 32768;
        ushort* lb_ = la_ + 16384;
        bf16x8 bv[4][2];
#pragma unroll
        for (int fn = 0; fn < 4; ++fn) {
            ushort* r = lb_ + (wc + fn * 16 + ml) * 64;
            bv[fn][0] = *reinterpret_cast<bf16x8*>(r + rdo0);
            bv[fn][1] = *reinterpret_cast<bf16x8*>(r + rdo1);
        }
#pragma unroll
        for (int mh = 0; mh < 2; ++mh) {         // split A-half: caps live regs
            bf16x8 af[4][2];
#pragma unroll
            for (int fm = 0; fm < 4; ++fm) {
                ushort* r = la_ + (wr + mh * 64 + fm * 16 + ml) * 64;
                af[fm][0] = *reinterpret_cast<bf16x8*>(r + rdo0);
                af[fm][1] = *reinterpret_cast<bf16x8*>(r + rdo1);
            }
            __builtin_amdgcn_s_setprio(1);
#pragma unroll
            for (int ks = 0; ks < 2; ++ks)
#pragma unroll
                for (int fm = 0; fm < 4; ++fm)
#pragma unroll
                    for (int fn = 0; fn < 4; ++fn)
                        acc[mh * 4 + fm][fn] = __builtin_amdgcn_mfma_f32_16x16x32_bf16(
                            af[fm][ks], bv[fn][ks], acc[mh * 4 + fm][fn], 0, 0, 0);
            __builtin_amdgcn_s_setprio(0);
        }
    };

    const int nkt = K >> 6;                       // = 8 for K=512
    stage(0, 0); SFENCE();                        // keep tile0 loads oldest
    stage(1, 1); SFENCE();
    for (int t = 0; t < nkt - 1; ++t) {
        asm volatile("s_waitcnt vmcnt(8)" ::: "memory");   // tile t ready; t+1 in flight
        blockbar();
        compute(t & 1);
        blockbar();                               // slot t&1 free for overwrite
        if (t + 2 < nkt) { stage(t + 2, t & 1); SFENCE(); }
    }
    asm volatile("s_waitcnt vmcnt(0)" ::: "memory");       // epilogue drain
    blockbar();
    compute((nkt - 1) & 1);
    // no barrier needed: epilogue scratch lives in slot0 bytes, final compute
    // read slot1, and each wave's epilogue region is private.

    // ---- epilogue via per-wave LDS transpose -> coalesced wide stores ----
    if (F32OUT) {
        float* ep = reinterpret_cast<float*>(smem) + w * 1088;   // 16 rows x 68 f32
        float bj[4];
#pragma unroll
        for (int j = 0; j < 4; ++j) bj[j] = bias[nBase + wc + j * 16 + ml];
        float* cbase = reinterpret_cast<float*>(Cout);
#pragma unroll
        for (int i = 0; i < 8; ++i) {
#pragma unroll
            for (int j = 0; j < 4; ++j)
#pragma unroll
                for (int r = 0; r < 4; ++r)
                    ep[(quad * 4 + r) * 68 + j * 16 + ml] = acc[i][j][r] + bj[j];
#pragma unroll
            for (int t = 0; t < 4; ++t) {
                int ch = quad + 4 * t;
                float4 v = *reinterpret_cast<const float4*>(ep + ml * 68 + ch * 4);
                *reinterpret_cast<float4*>(cbase
                    + (size_t)(mBase + wr + i * 16 + ml) * Ncols + nBase + wc + ch * 4) = v;
            }
        }
    } else {
        ushort* ep = smem + w * 1152;   // 16 rows x 72 bf16
#pragma unroll
        for (int i = 0; i < 8; ++i) {
#pragma unroll
            for (int j = 0; j < 4; ++j)
#pragma unroll
                for (int r = 0; r < 4; ++r)
                    ep[(quad * 4 + r) * 72 + j * 16 + ml] = f2bf(acc[i][j][r]);
#pragma unroll
            for (int t = 0; t < 2; ++t) {
                int ch = quad + 4 * t;
                bf16x8 v = *reinterpret_cast<const bf16x8*>(ep + ml * 72 + ch * 8);
                int row = mBase + wr + i * 16 + ml;
                if (!vt) {
                    *reinterpret_cast<bf16x8*>(reinterpret_cast<ushort*>(Cout)
                        + (size_t)row * Ncols + nBase + wc + ch * 8) = v;
                } else {
                    // row = d-global (h*64+d), cols = tokens; group = nBase>>9
                    *reinterpret_cast<bf16x8*>(vT
                        + ((size_t)((nBase >> 9) * 512 + row)) * 512
                        + (nBase & 511) + wc + ch * 8) = v;
                }
            }
        }
    }
}

// ---------------------------------------------------------------- flash attention
// qk: [32768][1024] bf16 (Q 0..511 pre-scaled by 0.125*log2e, K 512..1023).
// vT: [(b*8+g)*512 + h*64+d][512 tokens] bf16.  out: [32768][512] bf16.
// 8 waves / 512 threads / 256 q-rows per block, grid 1024. Decode qc=(id>>3)&1,
// bgh=(id&7)|((id>>4)<<3): siblings {base, base+8} same XCD, adjacent (r5-proven).
// K/V 2-slot double-buffer with the GEMM-PROVEN counted cross-barrier schedule:
// stage(t+2) after the post-compute barrier; entry s_waitcnt vmcnt(2). vmcnt
// never 0 in-loop.
// ROUND-10 FIX: r9's __launch_bounds__(512, 6) forced a ~85-reg unified
// VGPR+AGPR budget -> 40 arch VGPRs -> total spill (FETCH+WRITE 1.3 GB scratch,
// 340 us). Now (512, 2) -- the exact bound the GEMM has run spill-free since
// round 2. Budget 256; kernel needs ~120.
__global__ __launch_bounds__(512, 2) void attn_kernel(
        const ushort* __restrict__ qk, const ushort* __restrict__ vT,
        ushort* __restrict__ out) {
    __shared__ ushort k_lds[2][64 * 64];    // K tile [tok][d], XOR-swizzled chunks
    __shared__ ushort v_lds[2][64 * 64];    // V^T tile [d][tok], XOR-swizzled chunks
    __shared__ ushort p_lds[8 * 32 * 36];   // per-wave P [q=32][tok-half=32+pad4]
    const int tid = threadIdx.x;
    const int w = tid >> 6, lane = tid & 63, ml = lane & 15, quad = lane >> 4;
    const int id = blockIdx.x;
    const int qc = (id >> 3) & 1;
    const int bgh = (id & 7) | ((id >> 4) << 3);
    const int b = bgh >> 6, g = (bgh >> 3) & 7, h = bgh & 7;
    const int tb = b * 4096 + g * 512;
    const ushort* base  = qk + (size_t)tb * 1024 + h * 64;
    const ushort* vbase = vT + ((size_t)((b * 8 + g) * 512 + h * 64)) * 512;
    const int qOff = qc * 256 + w * 32;

    // Q fragments (B-operand for S^T: B[k=d=quad*8+j][n=q=ml]) -- 4 global
    // loads, issued FIRST (oldest in the vmcnt stream; covered by vmcnt(2)).
    bf16x8 qf[2][2];
#pragma unroll
    for (int qb = 0; qb < 2; ++qb)
#pragma unroll
        for (int ks = 0; ks < 2; ++ks)
            qf[qb][ks] = *reinterpret_cast<const bf16x8*>(
                base + (size_t)(qOff + qb * 16 + ml) * 1024 + ks * 32 + quad * 8);
    SFENCE();   // pin qf loads before staging in issue order

    // staging: wave w covers rows [w*8, w*8+8) of each 64-row tile: ONE
    // gload_lds16 per matrix per tile (8 waves x 8 rows = 64).
    const int srow = lane >> 3;                 // 0..7
    const int sch  = (lane & 7) ^ srow;
    const ushort* kp = base + (size_t)(w * 8 + srow) * 1024 + 512 + sch * 8;
    const ushort* vp = vbase + (size_t)(w * 8 + srow) * 512 + sch * 8;

    auto stage = [&](int kt, int slot) {         // 2 loads/wave -> vmcnt +2
        gload_lds16(kp + (size_t)(kt * 64) * 1024, k_lds[slot] + (w * 8) * 64);
        gload_lds16(vp + kt * 64,                  v_lds[slot] + (w * 8) * 64);
    };

    const bf16x8 onesf = {0x3f80, 0x3f80, 0x3f80, 0x3f80,
                          0x3f80, 0x3f80, 0x3f80, 0x3f80};   // bf16 1.0

    f32x4 z4 = {0.f, 0.f, 0.f, 0.f};
    f32x4 oacc[2][4];
    f32x4 sacc[2];           // row-sum accumulator (denominator), on MFMA pipe
#pragma unroll
    for (int qb = 0; qb < 2; ++qb) {
#pragma unroll
        for (int db = 0; db < 4; ++db) oacc[qb][db] = z4;
        sacc[qb] = z4;
    }

    ushort* pw = p_lds + w * 32 * 36;

    auto compute = [&](int buf) {
        // --- S^T = K.Q^T: A=K-frag A[m=tok][k=d], two ks(d)-slices
        f32x4 s[2][4];
#pragma unroll
        for (int qb = 0; qb < 2; ++qb)
#pragma unroll
            for (int kb = 0; kb < 4; ++kb) s[qb][kb] = z4;
#pragma unroll
        for (int ks = 0; ks < 2; ++ks) {
            bf16x8 kfs[4];
#pragma unroll
            for (int kb = 0; kb < 4; ++kb)
                kfs[kb] = *reinterpret_cast<bf16x8*>(
                    k_lds[buf] + (kb * 16 + ml) * 64 + (((ks * 4 + quad) ^ (ml & 7)) << 3));
            __builtin_amdgcn_s_setprio(1);
#pragma unroll
            for (int qb = 0; qb < 2; ++qb)
#pragma unroll
                for (int kb = 0; kb < 4; ++kb)
                    s[qb][kb] = __builtin_amdgcn_mfma_f32_16x16x32_bf16(kfs[kb], qf[qb][ks], s[qb][kb], 0, 0, 0);
            __builtin_amdgcn_s_setprio(0);
        }

        // --- per tok-half (ks): exp2 + pack + P-write, then O += P.V / den += P.1
        // (P half written & consumed before ks=1 overwrites: same-wave in-order DS)
#pragma unroll
        for (int ks = 0; ks < 2; ++ks) {
#pragma unroll
            for (int qb = 0; qb < 2; ++qb)
#pragma unroll
                for (int kbh = 0; kbh < 2; ++kbh) {
                    int kb = ks * 2 + kbh;
                    float p0 = fexp2(s[qb][kb][0]), p1 = fexp2(s[qb][kb][1]);
                    float p2 = fexp2(s[qb][kb][2]), p3 = fexp2(s[qb][kb][3]);
                    uint2 pk2;
                    pk2.x = cvt_pk_bf16(p0, p1);
                    pk2.y = cvt_pk_bf16(p2, p3);
                    *reinterpret_cast<uint2*>(
                        pw + (qb * 16 + ml) * 36 + kbh * 16 + quad * 4) = pk2;
                }
            bf16x8 pfs[2], vfs[4];
#pragma unroll
            for (int qb = 0; qb < 2; ++qb)
                pfs[qb] = *reinterpret_cast<bf16x8*>(
                    pw + (qb * 16 + ml) * 36 + quad * 8);
#pragma unroll
            for (int db = 0; db < 4; ++db)
                vfs[db] = *reinterpret_cast<bf16x8*>(
                    v_lds[buf] + (db * 16 + ml) * 64 + (((ks * 4 + quad) ^ (ml & 7)) << 3));
            __builtin_amdgcn_s_setprio(1);
#pragma unroll
            for (int qb = 0; qb < 2; ++qb)
                sacc[qb] = __builtin_amdgcn_mfma_f32_16x16x32_bf16(pfs[qb], onesf, sacc[qb], 0, 0, 0);
#pragma unroll
            for (int qb = 0; qb < 2; ++qb)
#pragma unroll
                for (int db = 0; db < 4; ++db)
                    oacc[qb][db] = __builtin_amdgcn_mfma_f32_16x16x32_bf16(pfs[qb], vfs[db], oacc[qb][db], 0, 0, 0);
            __builtin_amdgcn_s_setprio(0);
        }
    };

    stage(0, 0); SFENCE();
    stage(1, 1); SFENCE();
    for (int kt = 0; kt < 7; ++kt) {
        asm volatile("s_waitcnt vmcnt(2)" ::: "memory");   // tile kt done; kt+1 in flight
        blockbar();
        compute(kt & 1);
        blockbar();                                        // slot kt&1 free for overwrite
        if (kt + 2 < 8) { stage(kt + 2, kt & 1); SFENCE(); }
    }
    asm volatile("s_waitcnt vmcnt(0)" ::: "memory");       // last tile drain
    blockbar();
    compute(1);                                            // tile 7 in slot 1

    // --- epilogue: lanes hold their rows' sums in sacc -- reciprocal, store.
    float invq[2][4];
#pragma unroll
    for (int qb = 0; qb < 2; ++qb)
#pragma unroll
        for (int r = 0; r < 4; ++r)
            invq[qb][r] = 1.0f / sacc[qb][r];
#pragma unroll
    for (int qb = 0; qb < 2; ++qb)
#pragma unroll
        for (int db = 0; db < 4; ++db)
#pragma unroll
            for (int r = 0; r < 4; ++r) {
                float v = oacc[qb][db][r] * invq[qb][r];
                out[(size_t)(tb + qOff + qb * 16 + quad * 4 + r) * 512
                    + h * 64 + db * 16 + ml] = f2bf(v);
            }
}

// ---------------------------------------------------------------- launch
extern "C" void kernel_launch(void* const* d_in, const int* in_sizes, int n_in,
                              void* d_out, int out_size, void* d_ws, size_t ws_size,
                              hipStream_t stream) {
    const float* x     = (const float*)d_in[0];   // [8,4096,512]
    const float* Wqkv  = (const float*)d_in[1];   // [512,1536]
    const float* Wproj = (const float*)d_in[2];   // [512,512]
    const float* bproj = (const float*)d_in[3];   // [512]
    // d_in[4] recursive_index == 0 (static) -> num_groups = 8

    char* ws = (char*)d_ws;
    ushort* xb   = (ushort*)(ws);              // 32768*512  bf16 = 33,554,432 B
    ushort* wq   = (ushort*)(ws + 33554432);   // 1536*512   bf16 =  1,572,864 B
    ushort* wp   = (ushort*)(ws + 35127296);   //  512*512   bf16 =    524,288 B
    ushort* qkb  = (ushort*)(ws + 35651584);   // 32768*1024 bf16 = 67,108,864 B (Q,K)
    ushort* vTb  = (ushort*)(ws + 102760448);  // 32768*512  bf16 = 33,554,432 B
    ushort* attn = xb;                         // alias: x_bf16 dead after GEMM1
    ushort* wv   = wq + 1024 * 512;            // V-rows of Wqkv^T: [512 d][512 c]
    float*  outp = (float*)d_out;

    prep_kernel<<<16640, 256, 0, stream>>>(x, xb, Wqkv, wq, Wproj, wp);
    gemm_bt_kernel<false, true><<<768, 512, 0, stream>>>(
        xb, wq, qkb, nullptr, wv, vTb, 1024, 512);
    attn_kernel<<<1024, 512, 0, stream>>>(qkb, vTb, attn);
    gemm_bt_kernel<true, false><<<256, 512, 0, stream>>>(
        attn, wp, outp, bproj, nullptr, nullptr, 512, 512);
}